// Round 19
// baseline (1923.721 us; speedup 1.0000x reference)
//
#include <hip/hip_runtime.h>
#include <hip/hip_bf16.h>
#include <cstdint>
#include <cstddef>

#define HP 320   // padded hidden/N dim (300 -> 320)

typedef unsigned short ushortT;
typedef __attribute__((ext_vector_type(8))) __bf16 bf16x8;
typedef __attribute__((ext_vector_type(4))) float f32x4;
typedef __attribute__((ext_vector_type(4))) unsigned int u32x4;
typedef __attribute__((ext_vector_type(4))) unsigned short u16x4;

__device__ __forceinline__ float b2f(unsigned u) {
    union { unsigned i; float f; } v; v.i = u << 16; return v.f;
}
__device__ __forceinline__ ushortT f2b(float f) {
    union { float f; unsigned i; } v; v.f = f;
    unsigned x = v.i;
    return (ushortT)((x + 0x7fffu + ((x >> 16) & 1u)) >> 16);
}
__device__ __forceinline__ unsigned subpk(unsigned a, unsigned r) {
    union { unsigned i; float f; } al, ah, rl, rh;
    al.i = a << 16; ah.i = a & 0xffff0000u;
    rl.i = r << 16; rh.i = r & 0xffff0000u;
    float lo = al.f - rl.f, hi = ah.f - rh.f;
    return (unsigned)f2b(lo) | ((unsigned)f2b(hi) << 16);
}
__device__ __forceinline__ uint4 subpk4(uint4 a, uint4 r) {
    uint4 o;
    o.x = subpk(a.x, r.x); o.y = subpk(a.y, r.y);
    o.z = subpk(a.z, r.z); o.w = subpk(a.w, r.w);
    return o;
}
__device__ __forceinline__ void upadd(uint4 u, float* s) {
    s[0] += b2f(u.x & 0xffff); s[1] += b2f(u.x >> 16);
    s[2] += b2f(u.y & 0xffff); s[3] += b2f(u.y >> 16);
    s[4] += b2f(u.z & 0xffff); s[5] += b2f(u.z >> 16);
    s[6] += b2f(u.w & 0xffff); s[7] += b2f(u.w >> 16);
}
__device__ __forceinline__ uint4 pk8(const float* s) {
    uint4 o;
    o.x = (unsigned)f2b(s[0]) | ((unsigned)f2b(s[1]) << 16);
    o.y = (unsigned)f2b(s[2]) | ((unsigned)f2b(s[3]) << 16);
    o.z = (unsigned)f2b(s[4]) | ((unsigned)f2b(s[5]) << 16);
    o.w = (unsigned)f2b(s[6]) | ((unsigned)f2b(s[7]) << 16);
    return o;
}

// non-temporal (L2-bypassing) access for streaming/gather traffic -- keeps the
// packed weights L2-resident. Builtins need ext_vector_type, not HIP uint4.
__device__ __forceinline__ uint4 ntld(const ushortT* p) {
    u32x4 r = __builtin_nontemporal_load((const u32x4*)p);
    uint4 o; o.x = r.x; o.y = r.y; o.z = r.z; o.w = r.w; return o;
}
__device__ __forceinline__ void ntst(ushortT* p, uint4 v) {
    u32x4 r = {v.x, v.y, v.z, v.w};
    __builtin_nontemporal_store(r, (u32x4*)p);
}
__device__ __forceinline__ void ntst4(ushortT* p, ushort4 v) {
    u16x4 r = {v.x, v.y, v.z, v.w};
    __builtin_nontemporal_store(r, (u16x4*)p);
}
__device__ __forceinline__ ushort4 ntld4(const ushortT* p) {
    u16x4 r = __builtin_nontemporal_load((const u16x4*)p);
    ushort4 o; o.x = r.x; o.y = r.y; o.z = r.z; o.w = r.w; return o;
}

// ---------------------------------------------------------------- pack weights into MFMA B-fragment order
// packed[kt][nt(20)][kg(4)][col(16)][j(8)]  ==  W[kt*32+kg*8+j][nt*16+col]
__device__ __forceinline__ void pack_one(int idx, const float* __restrict__ W,
                                         int Ksrc, ushortT* __restrict__ dst) {
    int j = idx & 7, col = (idx >> 3) & 15, kg = (idx >> 7) & 3;
    int t = idx >> 9; int nt = t % 20, kt = t / 20;
    int k = kt * 32 + kg * 8 + j, n = nt * 16 + col;
    float v = (k < Ksrc && n < 300) ? W[k * 300 + n] : 0.f;
    dst[idx] = f2b(v);
}
// W_o remap: logical k<133 -> fa rows (src k), k in [160,460) -> amsg rows (src k-27), else 0
__device__ __forceinline__ void pack_wo(int idx, const float* __restrict__ W,
                                        ushortT* __restrict__ dst) {
    int j = idx & 7, col = (idx >> 3) & 15, kg = (idx >> 7) & 3;
    int t = idx >> 9; int nt = t % 20, kt = t / 20;
    int k = kt * 32 + kg * 8 + j, n = nt * 16 + col;
    int src = (k < 133) ? k : ((k >= 160 && k < 460) ? (k - 27) : -1);
    float v = (src >= 0 && n < 300) ? W[src * 300 + n] : 0.f;
    dst[idx] = f2b(v);
}

__global__ __launch_bounds__(256) void k_pack_weights(
    const float* __restrict__ Wi, const float* __restrict__ Wh,
    const float* __restrict__ Wo, const float* __restrict__ bo,
    ushortT* __restrict__ Wipk, ushortT* __restrict__ Whpk,
    ushortT* __restrict__ Wopk, float* __restrict__ bop) {
    int idx = blockIdx.x * 256 + threadIdx.x;
    if (idx < 51200)  pack_one(idx, Wi, 147, Wipk);   // K1 = 160 (5 ktiles)
    if (idx < 102400) pack_one(idx, Wh, 300, Whpk);   // K2 = 320 (10 ktiles)
    if (idx < 153600) pack_wo(idx, Wo, Wopk);         // K3 = 480 (15 ktiles)
    if (idx < HP) bop[idx] = (idx < 300) ? bo[idx] : 0.f;
}

// ---------------------------------------------------------------- pre-pack f_bonds fp32 -> bf16 [nB][160] (streaming)
__global__ __launch_bounds__(256) void k_pack_fb(
    const float* __restrict__ fb, ushortT* __restrict__ fbb, int nB) {
    int t = blockIdx.x * 256 + threadIdx.x;
    if (t >= nB * 20) return;
    int row = t / 20, q = t - row * 20;
    int k0 = q * 8;
    union { ushortT u[8]; uint4 v; } o;
#pragma unroll
    for (int j = 0; j < 8; j++) {
        int k = k0 + j;
        o.u[j] = (k < 147) ? f2b(__builtin_nontemporal_load(&fb[(size_t)row * 147 + k])) : (ushortT)0;
    }
    ntst(fbb + (size_t)row * 160 + k0, o.v);
}

// ---------------------------------------------------------------- unified MFMA GEMM (R14 geometry: wave = 64r x 80c)
// Serial panel staging only (anything live across the MFMA cluster spills --
// R9/R11/R16). acc[4][5]=80 AGPR + breg 40 VGPR is the full budget.
// All gather/stream traffic is NON-TEMPORAL; only LOADB (weights) caches in L2.
// MODE 0: panel <- fbb (K=160). B=Wipk.                 out: relu(A@Wi)
// MODE 1: panel <- amsg[b2a]-msg[b2revb] (K=320, idx in LDS), kt0-9; restage fbb;
//         kt10-14. B=[Whpk|Wipk].  out: relu(diff@Wh + fb@Wi)
// MODE 2: 2-phase panel [64][264] (33KB, 3 blocks/CU): K[0,256)=fa|amsg, kt0-7;
//         restage K[256,480); kt8-14. B=Wopk.  out: ah=relu(A@Wo+b)
template <int MODE, bool AUXP>
__global__ __launch_bounds__(256, 3) void k_mfma(
    const float* __restrict__ fa, const float* __restrict__ fb,
    const ushortT* __restrict__ aux,        // fbb
    const ushortT* __restrict__ amsg,       // MODE1/2: atom-summed messages
    const ushortT* __restrict__ msgin,      // MODE1: prev msg
    const int* __restrict__ b2a, const int* __restrict__ b2revb,
    const ushortT* __restrict__ Bpk1, const ushortT* __restrict__ Bpk2,
    const float* __restrict__ bop,
    ushortT* __restrict__ outp) {
    constexpr int KT = (MODE == 0) ? 5 : 15;
    constexpr int SPLIT = (MODE == 1) ? 10 : KT;
    constexpr int SP = (MODE == 0) ? 168 : ((MODE == 1) ? 328 : 264);
    __shared__ __align__(16) ushortT panel[64 * SP];   // 21 / 41 / 33 KB
    __shared__ int idxA[(MODE == 1) ? 64 : 1];
    __shared__ int idxR[(MODE == 1) ? 64 : 1];

    const int tid = threadIdx.x, wave = tid >> 6, lane = tid & 63;
    const int row0 = blockIdx.x * 64;
    const int kg8 = (lane >> 4) * 8;
    const int l15 = lane & 15;

    if (MODE == 1) {
        if (tid < 64) {
            idxA[tid] = b2a[row0 + tid];
            idxR[tid] = b2revb[row0 + tid];
        }
        __syncthreads();
    }

    f32x4 acc[4][5];
#pragma unroll
    for (int i = 0; i < 4; i++)
#pragma unroll
        for (int n = 0; n < 5; n++) acc[i][n] = (f32x4){0.f, 0.f, 0.f, 0.f};

    uint4 breg[2][5];
    const int boff = wave * 5 * 512 + (lane >> 4) * 128 + l15 * 8;

#define LOADB(kt, buf)                                                               \
    {                                                                                \
        const ushortT* bp = ((kt) < SPLIT) ? (Bpk1 + (size_t)(kt) * 10240)           \
                                           : (Bpk2 + (size_t)((kt) - SPLIT) * 10240);\
        _Pragma("unroll")                                                            \
        for (int n = 0; n < 5; n++)                                                  \
            breg[buf][n] = *(const uint4*)(bp + boff + n * 512);                     \
    }

#define MSTEP(bufi, pk0)                                                             \
    {                                                                                \
        bf16x8 a0 = *(bf16x8*)&panel[(l15) * SP + (pk0) + kg8];                      \
        bf16x8 a1 = *(bf16x8*)&panel[(16 + l15) * SP + (pk0) + kg8];                 \
        bf16x8 a2 = *(bf16x8*)&panel[(32 + l15) * SP + (pk0) + kg8];                 \
        bf16x8 a3 = *(bf16x8*)&panel[(48 + l15) * SP + (pk0) + kg8];                 \
        __builtin_amdgcn_s_setprio(1);                                               \
        _Pragma("unroll")                                                            \
        for (int n = 0; n < 5; n++) {                                                \
            bf16x8 b;                                                                \
            *(uint4*)&b = breg[bufi][n];                                             \
            acc[0][n] = __builtin_amdgcn_mfma_f32_16x16x32_bf16(b, a0, acc[0][n], 0, 0, 0); \
            acc[1][n] = __builtin_amdgcn_mfma_f32_16x16x32_bf16(b, a1, acc[1][n], 0, 0, 0); \
            acc[2][n] = __builtin_amdgcn_mfma_f32_16x16x32_bf16(b, a2, acc[2][n], 0, 0, 0); \
            acc[3][n] = __builtin_amdgcn_mfma_f32_16x16x32_bf16(b, a3, acc[3][n], 0, 0, 0); \
        }                                                                            \
        __builtin_amdgcn_s_setprio(0);                                               \
    }

#define BUILD_FEAT(src, FD, row, ch, vout)                                           \
    {                                                                                \
        union { ushortT u[8]; uint4 w; } t;                                          \
        _Pragma("unroll")                                                            \
        for (int j = 0; j < 8; j++) {                                                \
            int k = (ch) * 8 + j;                                                    \
            t.u[j] = (k < FD) ? f2b(__builtin_nontemporal_load(&src[(size_t)(row) * FD + k])) : (ushortT)0; \
        }                                                                            \
        vout = t.w;                                                                  \
    }

    if (MODE == 0) {
        // ---- stage fbb (K=160), uint4 aligned loads
#pragma unroll
        for (int it = 0; it < 5; it++) {
            int flat = tid + 256 * it;
            int row = flat / 20, ch = flat - row * 20;
            uint4 v;
            if (AUXP) {
                v = ntld(aux + (size_t)(row0 + row) * 160 + ch * 8);
            } else {
                BUILD_FEAT(fb, 147, row0 + row, ch, v);
            }
            *(uint4*)&panel[row * SP + ch * 8] = v;
        }
        LOADB(0, 0);
        __syncthreads();
#pragma unroll
        for (int kt = 0; kt < 5; kt++) {
            if (kt + 1 < 5) LOADB(kt + 1, (kt + 1) & 1);
            MSTEP(kt & 1, kt * 32);
        }
    } else if (MODE == 1) {
        // ---- stage diff panel (full K=320), serial (spill-free pattern)
#pragma unroll
        for (int it = 0; it < 10; it++) {
            int flat = tid + 256 * it;             // 64 rows * 40 chunks
            int row = flat / 40, ch = flat - row * 40;
            uint4 ua = ntld(amsg + (size_t)idxA[row] * HP + ch * 8);
            uint4 ur = ntld(msgin + (size_t)idxR[row] * HP + ch * 8);
            *(uint4*)&panel[row * SP + ch * 8] = subpk4(ua, ur);
        }
        LOADB(0, 0);
        __syncthreads();
        // phase 1: gathered diff @ Wh (kt 0..9)
#pragma unroll
        for (int kt = 0; kt < 10; kt++) {
            LOADB(kt + 1, (kt + 1) & 1);
            MSTEP(kt & 1, kt * 32);
        }
        __syncthreads();                           // all panel readers done
        // restage fbb into dead cols [0,160)
#pragma unroll
        for (int it = 0; it < 5; it++) {
            int flat = tid + 256 * it;
            int row = flat / 20, ch = flat - row * 20;
            uint4 v;
            if (AUXP) {
                v = ntld(aux + (size_t)(row0 + row) * 160 + ch * 8);
            } else {
                BUILD_FEAT(fb, 147, row0 + row, ch, v);
            }
            *(uint4*)&panel[row * SP + ch * 8] = v;
        }
        __syncthreads();
        // phase 2: fbb @ Wi (kt 10..14)
#pragma unroll
        for (int kt = 10; kt < 15; kt++) {
            if (kt + 1 < 15) LOADB(kt + 1, (kt + 1) & 1);
            MSTEP(kt & 1, (kt - 10) * 32);
        }
    } else {
        // ---- MODE 2, 2-phase panel (33 KB): phase 1 = K[0,256) = fa | amsg[0,96)
#pragma unroll
        for (int it = 0; it < 8; it++) {
            int flat = tid + 256 * it;             // 64 rows * 32 chunks
            int row = flat / 32, ch = flat - row * 32;
            uint4 v;
            if (ch >= 20) {
                v = ntld(amsg + (size_t)(row0 + row) * HP + (ch - 20) * 8);
            } else {
                BUILD_FEAT(fa, 133, row0 + row, ch, v);
            }
            *(uint4*)&panel[row * SP + ch * 8] = v;
        }
        LOADB(0, 0);
        __syncthreads();
#pragma unroll
        for (int kt = 0; kt < 8; kt++) {
            LOADB(kt + 1, (kt + 1) & 1);
            MSTEP(kt & 1, kt * 32);
        }
        __syncthreads();                           // phase-1 readers done
        // phase 2 staging: K[256,480) = amsg[96,320)  (28 chunks/row)
#pragma unroll
        for (int it = 0; it < 7; it++) {
            int flat = tid + 256 * it;             // 64 rows * 28 chunks
            int row = flat / 28, ch = flat - row * 28;
            uint4 v = ntld(amsg + (size_t)(row0 + row) * HP + 96 + ch * 8);
            *(uint4*)&panel[row * SP + ch * 8] = v;
        }
        __syncthreads();
#pragma unroll
        for (int kt = 8; kt < 15; kt++) {
            if (kt + 1 < 15) LOADB(kt + 1, (kt + 1) & 1);
            MSTEP(kt & 1, (kt - 8) * 32);
        }
    }
#undef LOADB
#undef MSTEP
#undef BUILD_FEAT

    // ================= epilogue (non-temporal stores): C[row = l15 (+16i)][cols wave*80 + n*16 + (lane>>4)*4]
#pragma unroll
    for (int i = 0; i < 4; i++) {
        size_t gr = (size_t)(row0 + i * 16 + l15);
#pragma unroll
        for (int n = 0; n < 5; n++) {
            int col = wave * 80 + n * 16 + (lane >> 4) * 4;
            float4 v = make_float4(acc[i][n][0], acc[i][n][1], acc[i][n][2], acc[i][n][3]);
            if (MODE == 2) {
                float4 bias = *(const float4*)&bop[col];
                v.x += bias.x; v.y += bias.y; v.z += bias.z; v.w += bias.w;
            }
            ushort4 u;
            u.x = f2b(fmaxf(v.x, 0.f)); u.y = f2b(fmaxf(v.y, 0.f));
            u.z = f2b(fmaxf(v.z, 0.f)); u.w = f2b(fmaxf(v.w, 0.f));
            ntst4(&outp[gr * HP + col], u);
        }
    }
}

// ---------------------------------------------------------------- atom sum (bf16 in/out, fp32 accum), all non-temporal
__global__ __launch_bounds__(256) void k_atom_sum(
    const ushortT* __restrict__ msg, const int* __restrict__ a2b,
    ushortT* __restrict__ amsg, int nA) {
    int t = blockIdx.x * 256 + threadIdx.x;
    int a = t / 40, q = t - a * 40;
    if (a >= nA) return;
    float s[8];
#pragma unroll
    for (int e = 0; e < 8; e++) s[e] = 0.f;
#pragma unroll
    for (int j = 0; j < 6; j++) {
        int b = a2b[a * 6 + j];
        uint4 u = ntld(msg + (size_t)b * HP + q * 8);
        upadd(u, s);
    }
    ntst(amsg + (size_t)a * HP + q * 8, pk8(s));
}

// ---------------------------------------------------------------- mean pool (bf16 ah -> fp32 out), vectorized
__global__ __launch_bounds__(256) void k_pool(
    const ushortT* __restrict__ ah, float* __restrict__ out, int n_mols, int apm) {
    int t = blockIdx.x * 256 + threadIdx.x;
    int m = t / 75, c4 = t - m * 75;    // 75 float4-chunks of 300 cols
    if (m >= n_mols) return;
    float4 s = make_float4(0, 0, 0, 0);
    for (int u = 0; u < apm; u++) {
        ushort4 q = ntld4(&ah[(size_t)(m * apm + u) * HP + c4 * 4]);
        s.x += b2f(q.x); s.y += b2f(q.y); s.z += b2f(q.z); s.w += b2f(q.w);
    }
    float inv = 1.0f / (float)apm;
    s.x *= inv; s.y *= inv; s.z *= inv; s.w *= inv;
    *(float4*)&out[(size_t)m * 300 + c4 * 4] = s;
}

// ---------------------------------------------------------------- launch
extern "C" void kernel_launch(void* const* d_in, const int* in_sizes, int n_in,
                              void* d_out, int out_size, void* d_ws, size_t ws_size,
                              hipStream_t stream) {
    const float* fa     = (const float*)d_in[0];
    const float* fb     = (const float*)d_in[1];
    const int*   a2b    = (const int*)d_in[2];
    const int*   b2a    = (const int*)d_in[3];
    const int*   b2revb = (const int*)d_in[4];
    const float* Wi     = (const float*)d_in[5];
    const float* Wh     = (const float*)d_in[6];
    const float* Wo     = (const float*)d_in[7];
    const float* bo     = (const float*)d_in[8];

    const int nA     = in_sizes[0] / 133;   // 200000
    const int nB     = in_sizes[1] / 147;   // 400000
    const int n_mols = out_size / 300;      // 10000
    const int apm    = nA / n_mols;         // 20

    char* p = (char*)d_ws;
    ushortT* Wipk = (ushortT*)p;  p += (size_t)51200 * 2;
    ushortT* Whpk = (ushortT*)p;  p += (size_t)102400 * 2;
    ushortT* Wopk = (ushortT*)p;  p += (size_t)153600 * 2;
    float*   bop  = (float*)p;    p += (size_t)HP * 4;
    p = (char*)(((uintptr_t)p + 255) & ~(uintptr_t)255);

    const size_t msgBytes  = (size_t)nB * HP * 2;
    const size_t amsgBytes = (size_t)nA * HP * 2;
    const size_t fbbBytes  = (size_t)nB * 160 * 2;
    const size_t headBytes = (size_t)(p - (char*)d_ws);
    const bool use_fbb = ws_size >= headBytes + 2 * msgBytes + amsgBytes + fbbBytes;

    ushortT* msgA = (ushortT*)p;  p += msgBytes;
    ushortT* msgB = (ushortT*)p;  p += msgBytes;
    ushortT* amsg = (ushortT*)p;  p += amsgBytes;
    ushortT* fbb  = use_fbb ? (ushortT*)p : nullptr;
    ushortT* ah   = msgB;           // msgB dead after depth-2 MODE1 consumes it
    float*   out  = (float*)d_out;

    k_pack_weights<<<600, 256, 0, stream>>>(Wi, Wh, Wo, bo, Wipk, Whpk, Wopk, bop);
    if (use_fbb)
        k_pack_fb<<<(nB * 20 + 255) / 256, 256, 0, stream>>>(fb, fbb, nB);

    const int asum_grid = (int)(((size_t)nA * 40 + 255) / 256);
    const int gB = nB / 64, gA = nA / 64;

    // GEMM1: msgA = relu(fbb @ Wi)
    if (use_fbb)
        k_mfma<0, true ><<<gB, 256, 0, stream>>>(fa, fb, fbb, nullptr, nullptr, nullptr, nullptr,
                                                 Wipk, Wipk, bop, msgA);
    else
        k_mfma<0, false><<<gB, 256, 0, stream>>>(fa, fb, nullptr, nullptr, nullptr, nullptr, nullptr,
                                                 Wipk, Wipk, bop, msgA);

    // depth 1: msgA -> msgB
    k_atom_sum<<<asum_grid, 256, 0, stream>>>(msgA, a2b, amsg, nA);
    if (use_fbb)
        k_mfma<1, true ><<<gB, 256, 0, stream>>>(fa, fb, fbb, amsg, msgA, b2a, b2revb,
                                                 Whpk, Wipk, bop, msgB);
    else
        k_mfma<1, false><<<gB, 256, 0, stream>>>(fa, fb, nullptr, amsg, msgA, b2a, b2revb,
                                                 Whpk, Wipk, bop, msgB);

    // depth 2: msgB -> msgA
    k_atom_sum<<<asum_grid, 256, 0, stream>>>(msgB, a2b, amsg, nA);
    if (use_fbb)
        k_mfma<1, true ><<<gB, 256, 0, stream>>>(fa, fb, fbb, amsg, msgB, b2a, b2revb,
                                                 Whpk, Wipk, bop, msgA);
    else
        k_mfma<1, false><<<gB, 256, 0, stream>>>(fa, fb, nullptr, amsg, msgB, b2a, b2revb,
                                                 Whpk, Wipk, bop, msgA);

    // readout: amsg = atomsum(msgA); ah = relu(concat(fa, amsg) @ Wo + b)
    k_atom_sum<<<asum_grid, 256, 0, stream>>>(msgA, a2b, amsg, nA);
    k_mfma<2, false><<<gA, 256, 0, stream>>>(fa, fb, nullptr, amsg, nullptr, nullptr, nullptr,
                                             Wopk, Wopk, bop, ah);
    k_pool<<<((n_mols * 75) + 255) / 256, 256, 0, stream>>>(ah, out, n_mols, apm);
}

// Round 20
// 1347.602 us; speedup vs baseline: 1.4275x; 1.4275x over previous
//
#include <hip/hip_runtime.h>
#include <hip/hip_bf16.h>
#include <cstdint>
#include <cstddef>

#define HP 320   // padded hidden/N dim (300 -> 320)

typedef unsigned short ushortT;
typedef __attribute__((ext_vector_type(8))) __bf16 bf16x8;
typedef __attribute__((ext_vector_type(4))) float f32x4;

__device__ __forceinline__ float b2f(unsigned u) {
    union { unsigned i; float f; } v; v.i = u << 16; return v.f;
}
__device__ __forceinline__ ushortT f2b(float f) {
    union { float f; unsigned i; } v; v.f = f;
    unsigned x = v.i;
    return (ushortT)((x + 0x7fffu + ((x >> 16) & 1u)) >> 16);
}
__device__ __forceinline__ unsigned subpk(unsigned a, unsigned r) {
    union { unsigned i; float f; } al, ah, rl, rh;
    al.i = a << 16; ah.i = a & 0xffff0000u;
    rl.i = r << 16; rh.i = r & 0xffff0000u;
    float lo = al.f - rl.f, hi = ah.f - rh.f;
    return (unsigned)f2b(lo) | ((unsigned)f2b(hi) << 16);
}
__device__ __forceinline__ uint4 subpk4(uint4 a, uint4 r) {
    uint4 o;
    o.x = subpk(a.x, r.x); o.y = subpk(a.y, r.y);
    o.z = subpk(a.z, r.z); o.w = subpk(a.w, r.w);
    return o;
}
__device__ __forceinline__ void upadd(uint4 u, float* s) {
    s[0] += b2f(u.x & 0xffff); s[1] += b2f(u.x >> 16);
    s[2] += b2f(u.y & 0xffff); s[3] += b2f(u.y >> 16);
    s[4] += b2f(u.z & 0xffff); s[5] += b2f(u.z >> 16);
    s[6] += b2f(u.w & 0xffff); s[7] += b2f(u.w >> 16);
}
__device__ __forceinline__ uint4 pk8(const float* s) {
    uint4 o;
    o.x = (unsigned)f2b(s[0]) | ((unsigned)f2b(s[1]) << 16);
    o.y = (unsigned)f2b(s[2]) | ((unsigned)f2b(s[3]) << 16);
    o.z = (unsigned)f2b(s[4]) | ((unsigned)f2b(s[5]) << 16);
    o.w = (unsigned)f2b(s[6]) | ((unsigned)f2b(s[7]) << 16);
    return o;
}

// ---------------------------------------------------------------- pack weights into MFMA B-fragment order
// packed[kt][nt(20)][kg(4)][col(16)][j(8)]  ==  W[kt*32+kg*8+j][nt*16+col]
__device__ __forceinline__ void pack_one(int idx, const float* __restrict__ W,
                                         int Ksrc, ushortT* __restrict__ dst) {
    int j = idx & 7, col = (idx >> 3) & 15, kg = (idx >> 7) & 3;
    int t = idx >> 9; int nt = t % 20, kt = t / 20;
    int k = kt * 32 + kg * 8 + j, n = nt * 16 + col;
    float v = (k < Ksrc && n < 300) ? W[k * 300 + n] : 0.f;
    dst[idx] = f2b(v);
}
// W_o remap: logical k<133 -> fa rows (src k), k in [160,460) -> amsg rows (src k-27), else 0
__device__ __forceinline__ void pack_wo(int idx, const float* __restrict__ W,
                                        ushortT* __restrict__ dst) {
    int j = idx & 7, col = (idx >> 3) & 15, kg = (idx >> 7) & 3;
    int t = idx >> 9; int nt = t % 20, kt = t / 20;
    int k = kt * 32 + kg * 8 + j, n = nt * 16 + col;
    int src = (k < 133) ? k : ((k >= 160 && k < 460) ? (k - 27) : -1);
    float v = (src >= 0 && n < 300) ? W[src * 300 + n] : 0.f;
    dst[idx] = f2b(v);
}

__global__ __launch_bounds__(256) void k_pack_weights(
    const float* __restrict__ Wi, const float* __restrict__ Wh,
    const float* __restrict__ Wo, const float* __restrict__ bo,
    ushortT* __restrict__ Wipk, ushortT* __restrict__ Whpk,
    ushortT* __restrict__ Wopk, float* __restrict__ bop) {
    int idx = blockIdx.x * 256 + threadIdx.x;
    if (idx < 51200)  pack_one(idx, Wi, 147, Wipk);   // K1 = 160 (5 ktiles)
    if (idx < 102400) pack_one(idx, Wh, 300, Whpk);   // K2 = 320 (10 ktiles)
    if (idx < 153600) pack_wo(idx, Wo, Wopk);         // K3 = 480 (15 ktiles)
    if (idx < HP) bop[idx] = (idx < 300) ? bo[idx] : 0.f;
}

// ---------------------------------------------------------------- pre-pack f_bonds fp32 -> bf16 [nB][160] (streaming)
__global__ __launch_bounds__(256) void k_pack_fb(
    const float* __restrict__ fb, ushortT* __restrict__ fbb, int nB) {
    int t = blockIdx.x * 256 + threadIdx.x;
    if (t >= nB * 20) return;
    int row = t / 20, q = t - row * 20;
    int k0 = q * 8;
    union { ushortT u[8]; uint4 v; } o;
#pragma unroll
    for (int j = 0; j < 8; j++) {
        int k = k0 + j;
        o.u[j] = (k < 147) ? f2b(fb[(size_t)row * 147 + k]) : (ushortT)0;
    }
    *(uint4*)(fbb + (size_t)row * 160 + k0) = o.v;
}

// ---------------------------------------------------------------- unified MFMA GEMM (R14 geometry: wave = 64r x 80c)
// Serial panel staging only (anything live across the MFMA cluster spills --
// R9/R11/R16). acc[4][5]=80 AGPR + breg 40 VGPR is the full budget.
// Plain cached loads/stores (NT measured 2x write amplification, R19).
// MODE 0: panel <- fbb (K=160). B=Wipk.                 out: relu(A@Wi)
// MODE 1: panel <- amsg[b2a]-msg[b2revb] (K=320, idx in LDS), kt0-9; restage fbb;
//         kt10-14. B=[Whpk|Wipk].  out: relu(diff@Wh + fb@Wi)
// MODE 2: 2-phase panel [64][264] (33KB, 3 blocks/CU): K[0,256)=fa|amsg, kt0-7;
//         restage K[256,480); kt8-14. B=Wopk.  out: ah=relu(A@Wo+b)
template <int MODE, bool AUXP>
__global__ __launch_bounds__(256, 3) void k_mfma(
    const float* __restrict__ fa, const float* __restrict__ fb,
    const ushortT* __restrict__ aux,        // fbb
    const ushortT* __restrict__ amsg,       // MODE1/2: atom-summed messages
    const ushortT* __restrict__ msgin,      // MODE1: prev msg
    const int* __restrict__ b2a, const int* __restrict__ b2revb,
    const ushortT* __restrict__ Bpk1, const ushortT* __restrict__ Bpk2,
    const float* __restrict__ bop,
    ushortT* __restrict__ outp) {
    constexpr int KT = (MODE == 0) ? 5 : 15;
    constexpr int SPLIT = (MODE == 1) ? 10 : KT;
    constexpr int SP = (MODE == 0) ? 168 : ((MODE == 1) ? 328 : 264);
    __shared__ __align__(16) ushortT panel[64 * SP];   // 21 / 41 / 33 KB
    __shared__ int idxA[(MODE == 1) ? 64 : 1];
    __shared__ int idxR[(MODE == 1) ? 64 : 1];

    const int tid = threadIdx.x, wave = tid >> 6, lane = tid & 63;
    const int row0 = blockIdx.x * 64;
    const int kg8 = (lane >> 4) * 8;
    const int l15 = lane & 15;

    if (MODE == 1) {
        if (tid < 64) {
            idxA[tid] = b2a[row0 + tid];
            idxR[tid] = b2revb[row0 + tid];
        }
        __syncthreads();
    }

    f32x4 acc[4][5];
#pragma unroll
    for (int i = 0; i < 4; i++)
#pragma unroll
        for (int n = 0; n < 5; n++) acc[i][n] = (f32x4){0.f, 0.f, 0.f, 0.f};

    uint4 breg[2][5];
    const int boff = wave * 5 * 512 + (lane >> 4) * 128 + l15 * 8;

#define LOADB(kt, buf)                                                               \
    {                                                                                \
        const ushortT* bp = ((kt) < SPLIT) ? (Bpk1 + (size_t)(kt) * 10240)           \
                                           : (Bpk2 + (size_t)((kt) - SPLIT) * 10240);\
        _Pragma("unroll")                                                            \
        for (int n = 0; n < 5; n++)                                                  \
            breg[buf][n] = *(const uint4*)(bp + boff + n * 512);                     \
    }

#define MSTEP(bufi, pk0)                                                             \
    {                                                                                \
        bf16x8 a0 = *(bf16x8*)&panel[(l15) * SP + (pk0) + kg8];                      \
        bf16x8 a1 = *(bf16x8*)&panel[(16 + l15) * SP + (pk0) + kg8];                 \
        bf16x8 a2 = *(bf16x8*)&panel[(32 + l15) * SP + (pk0) + kg8];                 \
        bf16x8 a3 = *(bf16x8*)&panel[(48 + l15) * SP + (pk0) + kg8];                 \
        __builtin_amdgcn_s_setprio(1);                                               \
        _Pragma("unroll")                                                            \
        for (int n = 0; n < 5; n++) {                                                \
            bf16x8 b;                                                                \
            *(uint4*)&b = breg[bufi][n];                                             \
            acc[0][n] = __builtin_amdgcn_mfma_f32_16x16x32_bf16(b, a0, acc[0][n], 0, 0, 0); \
            acc[1][n] = __builtin_amdgcn_mfma_f32_16x16x32_bf16(b, a1, acc[1][n], 0, 0, 0); \
            acc[2][n] = __builtin_amdgcn_mfma_f32_16x16x32_bf16(b, a2, acc[2][n], 0, 0, 0); \
            acc[3][n] = __builtin_amdgcn_mfma_f32_16x16x32_bf16(b, a3, acc[3][n], 0, 0, 0); \
        }                                                                            \
        __builtin_amdgcn_s_setprio(0);                                               \
    }

#define BUILD_FEAT(src, FD, row, ch, vout)                                           \
    {                                                                                \
        union { ushortT u[8]; uint4 w; } t;                                          \
        _Pragma("unroll")                                                            \
        for (int j = 0; j < 8; j++) {                                                \
            int k = (ch) * 8 + j;                                                    \
            t.u[j] = (k < FD) ? f2b(src[(size_t)(row) * FD + k]) : (ushortT)0;       \
        }                                                                            \
        vout = t.w;                                                                  \
    }

    if (MODE == 0) {
        // ---- stage fbb (K=160), uint4 aligned loads
#pragma unroll
        for (int it = 0; it < 5; it++) {
            int flat = tid + 256 * it;
            int row = flat / 20, ch = flat - row * 20;
            uint4 v;
            if (AUXP) {
                v = *(const uint4*)(aux + (size_t)(row0 + row) * 160 + ch * 8);
            } else {
                BUILD_FEAT(fb, 147, row0 + row, ch, v);
            }
            *(uint4*)&panel[row * SP + ch * 8] = v;
        }
        LOADB(0, 0);
        __syncthreads();
#pragma unroll
        for (int kt = 0; kt < 5; kt++) {
            if (kt + 1 < 5) LOADB(kt + 1, (kt + 1) & 1);
            MSTEP(kt & 1, kt * 32);
        }
    } else if (MODE == 1) {
        // ---- stage diff panel (full K=320), serial (spill-free pattern)
#pragma unroll
        for (int it = 0; it < 10; it++) {
            int flat = tid + 256 * it;             // 64 rows * 40 chunks
            int row = flat / 40, ch = flat - row * 40;
            uint4 ua = *(const uint4*)(amsg + (size_t)idxA[row] * HP + ch * 8);
            uint4 ur = *(const uint4*)(msgin + (size_t)idxR[row] * HP + ch * 8);
            *(uint4*)&panel[row * SP + ch * 8] = subpk4(ua, ur);
        }
        LOADB(0, 0);
        __syncthreads();
        // phase 1: gathered diff @ Wh (kt 0..9)
#pragma unroll
        for (int kt = 0; kt < 10; kt++) {
            LOADB(kt + 1, (kt + 1) & 1);
            MSTEP(kt & 1, kt * 32);
        }
        __syncthreads();                           // all panel readers done
        // restage fbb into dead cols [0,160)
#pragma unroll
        for (int it = 0; it < 5; it++) {
            int flat = tid + 256 * it;
            int row = flat / 20, ch = flat - row * 20;
            uint4 v;
            if (AUXP) {
                v = *(const uint4*)(aux + (size_t)(row0 + row) * 160 + ch * 8);
            } else {
                BUILD_FEAT(fb, 147, row0 + row, ch, v);
            }
            *(uint4*)&panel[row * SP + ch * 8] = v;
        }
        __syncthreads();
        // phase 2: fbb @ Wi (kt 10..14)
#pragma unroll
        for (int kt = 10; kt < 15; kt++) {
            if (kt + 1 < 15) LOADB(kt + 1, (kt + 1) & 1);
            MSTEP(kt & 1, (kt - 10) * 32);
        }
    } else {
        // ---- MODE 2, 2-phase panel (33 KB): phase 1 = K[0,256) = fa | amsg[0,96)
#pragma unroll
        for (int it = 0; it < 8; it++) {
            int flat = tid + 256 * it;             // 64 rows * 32 chunks
            int row = flat / 32, ch = flat - row * 32;
            uint4 v;
            if (ch >= 20) {
                v = *(const uint4*)(amsg + (size_t)(row0 + row) * HP + (ch - 20) * 8);
            } else {
                BUILD_FEAT(fa, 133, row0 + row, ch, v);
            }
            *(uint4*)&panel[row * SP + ch * 8] = v;
        }
        LOADB(0, 0);
        __syncthreads();
#pragma unroll
        for (int kt = 0; kt < 8; kt++) {
            LOADB(kt + 1, (kt + 1) & 1);
            MSTEP(kt & 1, kt * 32);
        }
        __syncthreads();                           // phase-1 readers done
        // phase 2 staging: K[256,480) = amsg[96,320)  (28 chunks/row)
#pragma unroll
        for (int it = 0; it < 7; it++) {
            int flat = tid + 256 * it;             // 64 rows * 28 chunks
            int row = flat / 28, ch = flat - row * 28;
            uint4 v = *(const uint4*)(amsg + (size_t)(row0 + row) * HP + 96 + ch * 8);
            *(uint4*)&panel[row * SP + ch * 8] = v;
        }
        __syncthreads();
#pragma unroll
        for (int kt = 8; kt < 15; kt++) {
            if (kt + 1 < 15) LOADB(kt + 1, (kt + 1) & 1);
            MSTEP(kt & 1, (kt - 8) * 32);
        }
    }
#undef LOADB
#undef MSTEP
#undef BUILD_FEAT

    // ================= epilogue: C[row = l15 (+16i)][cols wave*80 + n*16 + (lane>>4)*4]
#pragma unroll
    for (int i = 0; i < 4; i++) {
        size_t gr = (size_t)(row0 + i * 16 + l15);
#pragma unroll
        for (int n = 0; n < 5; n++) {
            int col = wave * 80 + n * 16 + (lane >> 4) * 4;
            float4 v = make_float4(acc[i][n][0], acc[i][n][1], acc[i][n][2], acc[i][n][3]);
            if (MODE == 2) {
                float4 bias = *(const float4*)&bop[col];
                v.x += bias.x; v.y += bias.y; v.z += bias.z; v.w += bias.w;
            }
            ushort4 u;
            u.x = f2b(fmaxf(v.x, 0.f)); u.y = f2b(fmaxf(v.y, 0.f));
            u.z = f2b(fmaxf(v.z, 0.f)); u.w = f2b(fmaxf(v.w, 0.f));
            *(ushort4*)&outp[gr * HP + col] = u;
        }
    }
}

// ---------------------------------------------------------------- atom sum (bf16 in/out, fp32 accum)
__global__ __launch_bounds__(256) void k_atom_sum(
    const ushortT* __restrict__ msg, const int* __restrict__ a2b,
    ushortT* __restrict__ amsg, int nA) {
    int t = blockIdx.x * 256 + threadIdx.x;
    int a = t / 40, q = t - a * 40;
    if (a >= nA) return;
    float s[8];
#pragma unroll
    for (int e = 0; e < 8; e++) s[e] = 0.f;
#pragma unroll
    for (int j = 0; j < 6; j++) {
        int b = a2b[a * 6 + j];
        uint4 u = *(const uint4*)(msg + (size_t)b * HP + q * 8);
        upadd(u, s);
    }
    *(uint4*)(amsg + (size_t)a * HP + q * 8) = pk8(s);
}

// ---------------------------------------------------------------- mean pool (bf16 ah -> fp32 out), vectorized
__global__ __launch_bounds__(256) void k_pool(
    const ushortT* __restrict__ ah, float* __restrict__ out, int n_mols, int apm) {
    int t = blockIdx.x * 256 + threadIdx.x;
    int m = t / 75, c4 = t - m * 75;    // 75 float4-chunks of 300 cols
    if (m >= n_mols) return;
    float4 s = make_float4(0, 0, 0, 0);
    for (int u = 0; u < apm; u++) {
        ushort4 q = *(const ushort4*)&ah[(size_t)(m * apm + u) * HP + c4 * 4];
        s.x += b2f(q.x); s.y += b2f(q.y); s.z += b2f(q.z); s.w += b2f(q.w);
    }
    float inv = 1.0f / (float)apm;
    s.x *= inv; s.y *= inv; s.z *= inv; s.w *= inv;
    *(float4*)&out[(size_t)m * 300 + c4 * 4] = s;
}

// ---------------------------------------------------------------- launch
extern "C" void kernel_launch(void* const* d_in, const int* in_sizes, int n_in,
                              void* d_out, int out_size, void* d_ws, size_t ws_size,
                              hipStream_t stream) {
    const float* fa     = (const float*)d_in[0];
    const float* fb     = (const float*)d_in[1];
    const int*   a2b    = (const int*)d_in[2];
    const int*   b2a    = (const int*)d_in[3];
    const int*   b2revb = (const int*)d_in[4];
    const float* Wi     = (const float*)d_in[5];
    const float* Wh     = (const float*)d_in[6];
    const float* Wo     = (const float*)d_in[7];
    const float* bo     = (const float*)d_in[8];

    const int nA     = in_sizes[0] / 133;   // 200000
    const int nB     = in_sizes[1] / 147;   // 400000
    const int n_mols = out_size / 300;      // 10000
    const int apm    = nA / n_mols;         // 20

    char* p = (char*)d_ws;
    ushortT* Wipk = (ushortT*)p;  p += (size_t)51200 * 2;
    ushortT* Whpk = (ushortT*)p;  p += (size_t)102400 * 2;
    ushortT* Wopk = (ushortT*)p;  p += (size_t)153600 * 2;
    float*   bop  = (float*)p;    p += (size_t)HP * 4;
    p = (char*)(((uintptr_t)p + 255) & ~(uintptr_t)255);

    const size_t msgBytes  = (size_t)nB * HP * 2;
    const size_t amsgBytes = (size_t)nA * HP * 2;
    const size_t fbbBytes  = (size_t)nB * 160 * 2;
    const size_t headBytes = (size_t)(p - (char*)d_ws);
    const bool use_fbb = ws_size >= headBytes + 2 * msgBytes + amsgBytes + fbbBytes;

    ushortT* msgA = (ushortT*)p;  p += msgBytes;
    ushortT* msgB = (ushortT*)p;  p += msgBytes;
    ushortT* amsg = (ushortT*)p;  p += amsgBytes;
    ushortT* fbb  = use_fbb ? (ushortT*)p : nullptr;
    ushortT* ah   = msgB;           // msgB dead after depth-2 MODE1 consumes it
    float*   out  = (float*)d_out;

    k_pack_weights<<<600, 256, 0, stream>>>(Wi, Wh, Wo, bo, Wipk, Whpk, Wopk, bop);
    if (use_fbb)
        k_pack_fb<<<(nB * 20 + 255) / 256, 256, 0, stream>>>(fb, fbb, nB);

    const int asum_grid = (int)(((size_t)nA * 40 + 255) / 256);
    const int gB = nB / 64, gA = nA / 64;

    // GEMM1: msgA = relu(fbb @ Wi)
    if (use_fbb)
        k_mfma<0, true ><<<gB, 256, 0, stream>>>(fa, fb, fbb, nullptr, nullptr, nullptr, nullptr,
                                                 Wipk, Wipk, bop, msgA);
    else
        k_mfma<0, false><<<gB, 256, 0, stream>>>(fa, fb, nullptr, nullptr, nullptr, nullptr, nullptr,
                                                 Wipk, Wipk, bop, msgA);

    // depth 1: msgA -> msgB
    k_atom_sum<<<asum_grid, 256, 0, stream>>>(msgA, a2b, amsg, nA);
    if (use_fbb)
        k_mfma<1, true ><<<gB, 256, 0, stream>>>(fa, fb, fbb, amsg, msgA, b2a, b2revb,
                                                 Whpk, Wipk, bop, msgB);
    else
        k_mfma<1, false><<<gB, 256, 0, stream>>>(fa, fb, nullptr, amsg, msgA, b2a, b2revb,
                                                 Whpk, Wipk, bop, msgB);

    // depth 2: msgB -> msgA
    k_atom_sum<<<asum_grid, 256, 0, stream>>>(msgB, a2b, amsg, nA);
    if (use_fbb)
        k_mfma<1, true ><<<gB, 256, 0, stream>>>(fa, fb, fbb, amsg, msgB, b2a, b2revb,
                                                 Whpk, Wipk, bop, msgA);
    else
        k_mfma<1, false><<<gB, 256, 0, stream>>>(fa, fb, nullptr, amsg, msgB, b2a, b2revb,
                                                 Whpk, Wipk, bop, msgA);

    // readout: amsg = atomsum(msgA); ah = relu(concat(fa, amsg) @ Wo + b)
    k_atom_sum<<<asum_grid, 256, 0, stream>>>(msgA, a2b, amsg, nA);
    k_mfma<2, false><<<gA, 256, 0, stream>>>(fa, fb, nullptr, amsg, nullptr, nullptr, nullptr,
                                             Wopk, Wopk, bop, ah);
    k_pool<<<((n_mols * 75) + 255) / 256, 256, 0, stream>>>(ah, out, n_mols, apm);
}

// Round 21
// 1324.555 us; speedup vs baseline: 1.4524x; 1.0174x over previous
//
#include <hip/hip_runtime.h>
#include <hip/hip_bf16.h>
#include <cstdint>
#include <cstddef>

#define HP 320   // padded hidden/N dim (300 -> 320)

typedef unsigned short ushortT;
typedef __attribute__((ext_vector_type(8))) __bf16 bf16x8;
typedef __attribute__((ext_vector_type(4))) float f32x4;

__device__ __forceinline__ float b2f(unsigned u) {
    union { unsigned i; float f; } v; v.i = u << 16; return v.f;
}
__device__ __forceinline__ ushortT f2b(float f) {
    union { float f; unsigned i; } v; v.f = f;
    unsigned x = v.i;
    return (ushortT)((x + 0x7fffu + ((x >> 16) & 1u)) >> 16);
}
__device__ __forceinline__ unsigned subpk(unsigned a, unsigned r) {
    union { unsigned i; float f; } al, ah, rl, rh;
    al.i = a << 16; ah.i = a & 0xffff0000u;
    rl.i = r << 16; rh.i = r & 0xffff0000u;
    float lo = al.f - rl.f, hi = ah.f - rh.f;
    return (unsigned)f2b(lo) | ((unsigned)f2b(hi) << 16);
}
__device__ __forceinline__ uint4 subpk4(uint4 a, uint4 r) {
    uint4 o;
    o.x = subpk(a.x, r.x); o.y = subpk(a.y, r.y);
    o.z = subpk(a.z, r.z); o.w = subpk(a.w, r.w);
    return o;
}
__device__ __forceinline__ void upadd(uint4 u, float* s) {
    s[0] += b2f(u.x & 0xffff); s[1] += b2f(u.x >> 16);
    s[2] += b2f(u.y & 0xffff); s[3] += b2f(u.y >> 16);
    s[4] += b2f(u.z & 0xffff); s[5] += b2f(u.z >> 16);
    s[6] += b2f(u.w & 0xffff); s[7] += b2f(u.w >> 16);
}
__device__ __forceinline__ uint4 pk8(const float* s) {
    uint4 o;
    o.x = (unsigned)f2b(s[0]) | ((unsigned)f2b(s[1]) << 16);
    o.y = (unsigned)f2b(s[2]) | ((unsigned)f2b(s[3]) << 16);
    o.z = (unsigned)f2b(s[4]) | ((unsigned)f2b(s[5]) << 16);
    o.w = (unsigned)f2b(s[6]) | ((unsigned)f2b(s[7]) << 16);
    return o;
}

// ---------------------------------------------------------------- pack weights into MFMA B-fragment order
// packed[kt][nt(20)][kg(4)][col(16)][j(8)]  ==  W[kt*32+kg*8+j][nt*16+col]
__device__ __forceinline__ void pack_one(int idx, const float* __restrict__ W,
                                         int Ksrc, ushortT* __restrict__ dst) {
    int j = idx & 7, col = (idx >> 3) & 15, kg = (idx >> 7) & 3;
    int t = idx >> 9; int nt = t % 20, kt = t / 20;
    int k = kt * 32 + kg * 8 + j, n = nt * 16 + col;
    float v = (k < Ksrc && n < 300) ? W[k * 300 + n] : 0.f;
    dst[idx] = f2b(v);
}
// W_o remap: logical k<133 -> fa rows (src k), k in [160,460) -> amsg rows (src k-27), else 0
__device__ __forceinline__ void pack_wo(int idx, const float* __restrict__ W,
                                        ushortT* __restrict__ dst) {
    int j = idx & 7, col = (idx >> 3) & 15, kg = (idx >> 7) & 3;
    int t = idx >> 9; int nt = t % 20, kt = t / 20;
    int k = kt * 32 + kg * 8 + j, n = nt * 16 + col;
    int src = (k < 133) ? k : ((k >= 160 && k < 460) ? (k - 27) : -1);
    float v = (src >= 0 && n < 300) ? W[src * 300 + n] : 0.f;
    dst[idx] = f2b(v);
}

__global__ __launch_bounds__(256) void k_pack_weights(
    const float* __restrict__ Wi, const float* __restrict__ Wh,
    const float* __restrict__ Wo, const float* __restrict__ bo,
    ushortT* __restrict__ Wipk, ushortT* __restrict__ Whpk,
    ushortT* __restrict__ Wopk, float* __restrict__ bop) {
    int idx = blockIdx.x * 256 + threadIdx.x;
    if (idx < 51200)  pack_one(idx, Wi, 147, Wipk);   // K1 = 160 (5 ktiles)
    if (idx < 102400) pack_one(idx, Wh, 300, Whpk);   // K2 = 320 (10 ktiles)
    if (idx < 153600) pack_wo(idx, Wo, Wopk);         // K3 = 480 (15 ktiles)
    if (idx < HP) bop[idx] = (idx < 300) ? bo[idx] : 0.f;
}

// ---------------------------------------------------------------- pre-pack fp32 features -> bf16 [rows][160] (streaming)
template <int FD>   // 147 (f_bonds) or 133 (f_atoms)
__global__ __launch_bounds__(256) void k_pack_feat(
    const float* __restrict__ src, ushortT* __restrict__ dst, int nrows) {
    int t = blockIdx.x * 256 + threadIdx.x;
    if (t >= nrows * 20) return;
    int row = t / 20, q = t - row * 20;
    int k0 = q * 8;
    union { ushortT u[8]; uint4 v; } o;
#pragma unroll
    for (int j = 0; j < 8; j++) {
        int k = k0 + j;
        o.u[j] = (k < FD) ? f2b(src[(size_t)row * FD + k]) : (ushortT)0;
    }
    *(uint4*)(dst + (size_t)row * 160 + k0) = o.v;
}

// ---------------------------------------------------------------- unified MFMA GEMM (R14 geometry: wave = 64r x 80c)
// Serial panel staging only (anything live across the MFMA cluster spills --
// R9/R11/R16). acc[4][5]=80 AGPR + breg 40 VGPR is the full budget.
// Plain cached loads/stores (NT measured 2x write amplification, R19).
// MODE 0: panel <- fbb (K=160). B=Wipk.                 out: relu(A@Wi)
// MODE 1: panel <- amsg[b2a]-msg[b2revb] (K=320, idx in LDS), kt0-9; restage fbb;
//         kt10-14. B=[Whpk|Wipk].  out: relu(diff@Wh + fb@Wi)
// MODE 2: 2-phase panel [64][264] (33KB, 3 blocks/CU): K[0,256)=faa|amsg, kt0-7;
//         restage K[256,480); kt8-14. B=Wopk.  out: ah=relu(A@Wo+b)
template <int MODE, bool AUXP>
__global__ __launch_bounds__(256, 3) void k_mfma(
    const float* __restrict__ fa, const float* __restrict__ fb,
    const ushortT* __restrict__ aux,        // MODE0/1: fbb ; MODE2: faa
    const ushortT* __restrict__ amsg,       // MODE1/2: atom-summed messages
    const ushortT* __restrict__ msgin,      // MODE1: prev msg
    const int* __restrict__ b2a, const int* __restrict__ b2revb,
    const ushortT* __restrict__ Bpk1, const ushortT* __restrict__ Bpk2,
    const float* __restrict__ bop,
    ushortT* __restrict__ outp) {
    constexpr int KT = (MODE == 0) ? 5 : 15;
    constexpr int SPLIT = (MODE == 1) ? 10 : KT;
    constexpr int SP = (MODE == 0) ? 168 : ((MODE == 1) ? 328 : 264);
    __shared__ __align__(16) ushortT panel[64 * SP];   // 21 / 41 / 33 KB
    __shared__ int idxA[(MODE == 1) ? 64 : 1];
    __shared__ int idxR[(MODE == 1) ? 64 : 1];

    const int tid = threadIdx.x, wave = tid >> 6, lane = tid & 63;
    const int row0 = blockIdx.x * 64;
    const int kg8 = (lane >> 4) * 8;
    const int l15 = lane & 15;

    if (MODE == 1) {
        if (tid < 64) {
            idxA[tid] = b2a[row0 + tid];
            idxR[tid] = b2revb[row0 + tid];
        }
        __syncthreads();
    }

    f32x4 acc[4][5];
#pragma unroll
    for (int i = 0; i < 4; i++)
#pragma unroll
        for (int n = 0; n < 5; n++) acc[i][n] = (f32x4){0.f, 0.f, 0.f, 0.f};

    uint4 breg[2][5];
    const int boff = wave * 5 * 512 + (lane >> 4) * 128 + l15 * 8;

#define LOADB(kt, buf)                                                               \
    {                                                                                \
        const ushortT* bp = ((kt) < SPLIT) ? (Bpk1 + (size_t)(kt) * 10240)           \
                                           : (Bpk2 + (size_t)((kt) - SPLIT) * 10240);\
        _Pragma("unroll")                                                            \
        for (int n = 0; n < 5; n++)                                                  \
            breg[buf][n] = *(const uint4*)(bp + boff + n * 512);                     \
    }

#define MSTEP(bufi, pk0)                                                             \
    {                                                                                \
        bf16x8 a0 = *(bf16x8*)&panel[(l15) * SP + (pk0) + kg8];                      \
        bf16x8 a1 = *(bf16x8*)&panel[(16 + l15) * SP + (pk0) + kg8];                 \
        bf16x8 a2 = *(bf16x8*)&panel[(32 + l15) * SP + (pk0) + kg8];                 \
        bf16x8 a3 = *(bf16x8*)&panel[(48 + l15) * SP + (pk0) + kg8];                 \
        __builtin_amdgcn_s_setprio(1);                                               \
        _Pragma("unroll")                                                            \
        for (int n = 0; n < 5; n++) {                                                \
            bf16x8 b;                                                                \
            *(uint4*)&b = breg[bufi][n];                                             \
            acc[0][n] = __builtin_amdgcn_mfma_f32_16x16x32_bf16(b, a0, acc[0][n], 0, 0, 0); \
            acc[1][n] = __builtin_amdgcn_mfma_f32_16x16x32_bf16(b, a1, acc[1][n], 0, 0, 0); \
            acc[2][n] = __builtin_amdgcn_mfma_f32_16x16x32_bf16(b, a2, acc[2][n], 0, 0, 0); \
            acc[3][n] = __builtin_amdgcn_mfma_f32_16x16x32_bf16(b, a3, acc[3][n], 0, 0, 0); \
        }                                                                            \
        __builtin_amdgcn_s_setprio(0);                                               \
    }

#define BUILD_FEAT(src, FD, row, ch, vout)                                           \
    {                                                                                \
        union { ushortT u[8]; uint4 w; } t;                                          \
        _Pragma("unroll")                                                            \
        for (int j = 0; j < 8; j++) {                                                \
            int k = (ch) * 8 + j;                                                    \
            t.u[j] = (k < FD) ? f2b(src[(size_t)(row) * FD + k]) : (ushortT)0;       \
        }                                                                            \
        vout = t.w;                                                                  \
    }

    if (MODE == 0) {
        // ---- stage fbb (K=160), uint4 aligned loads
#pragma unroll
        for (int it = 0; it < 5; it++) {
            int flat = tid + 256 * it;
            int row = flat / 20, ch = flat - row * 20;
            uint4 v;
            if (AUXP) {
                v = *(const uint4*)(aux + (size_t)(row0 + row) * 160 + ch * 8);
            } else {
                BUILD_FEAT(fb, 147, row0 + row, ch, v);
            }
            *(uint4*)&panel[row * SP + ch * 8] = v;
        }
        LOADB(0, 0);
        __syncthreads();
#pragma unroll
        for (int kt = 0; kt < 5; kt++) {
            if (kt + 1 < 5) LOADB(kt + 1, (kt + 1) & 1);
            MSTEP(kt & 1, kt * 32);
        }
    } else if (MODE == 1) {
        // ---- stage diff panel (full K=320), serial (spill-free pattern)
#pragma unroll
        for (int it = 0; it < 10; it++) {
            int flat = tid + 256 * it;             // 64 rows * 40 chunks
            int row = flat / 40, ch = flat - row * 40;
            uint4 ua = *(const uint4*)(amsg + (size_t)idxA[row] * HP + ch * 8);
            uint4 ur = *(const uint4*)(msgin + (size_t)idxR[row] * HP + ch * 8);
            *(uint4*)&panel[row * SP + ch * 8] = subpk4(ua, ur);
        }
        LOADB(0, 0);
        __syncthreads();
        // phase 1: gathered diff @ Wh (kt 0..9)
#pragma unroll
        for (int kt = 0; kt < 10; kt++) {
            LOADB(kt + 1, (kt + 1) & 1);
            MSTEP(kt & 1, kt * 32);
        }
        __syncthreads();                           // all panel readers done
        // restage fbb into dead cols [0,160)
#pragma unroll
        for (int it = 0; it < 5; it++) {
            int flat = tid + 256 * it;
            int row = flat / 20, ch = flat - row * 20;
            uint4 v;
            if (AUXP) {
                v = *(const uint4*)(aux + (size_t)(row0 + row) * 160 + ch * 8);
            } else {
                BUILD_FEAT(fb, 147, row0 + row, ch, v);
            }
            *(uint4*)&panel[row * SP + ch * 8] = v;
        }
        __syncthreads();
        // phase 2: fbb @ Wi (kt 10..14)
#pragma unroll
        for (int kt = 10; kt < 15; kt++) {
            if (kt + 1 < 15) LOADB(kt + 1, (kt + 1) & 1);
            MSTEP(kt & 1, (kt - 10) * 32);
        }
    } else {
        // ---- MODE 2, 2-phase panel (33 KB): phase 1 = K[0,256) = faa | amsg[0,96)
#pragma unroll
        for (int it = 0; it < 8; it++) {
            int flat = tid + 256 * it;             // 64 rows * 32 chunks
            int row = flat / 32, ch = flat - row * 32;
            uint4 v;
            if (ch >= 20) {
                v = *(const uint4*)(amsg + (size_t)(row0 + row) * HP + (ch - 20) * 8);
            } else if (AUXP) {
                v = *(const uint4*)(aux + (size_t)(row0 + row) * 160 + ch * 8);
            } else {
                BUILD_FEAT(fa, 133, row0 + row, ch, v);
            }
            *(uint4*)&panel[row * SP + ch * 8] = v;
        }
        LOADB(0, 0);
        __syncthreads();
#pragma unroll
        for (int kt = 0; kt < 8; kt++) {
            LOADB(kt + 1, (kt + 1) & 1);
            MSTEP(kt & 1, kt * 32);
        }
        __syncthreads();                           // phase-1 readers done
        // phase 2 staging: K[256,480) = amsg[96,320)  (28 chunks/row)
#pragma unroll
        for (int it = 0; it < 7; it++) {
            int flat = tid + 256 * it;             // 64 rows * 28 chunks
            int row = flat / 28, ch = flat - row * 28;
            uint4 v = *(const uint4*)(amsg + (size_t)(row0 + row) * HP + 96 + ch * 8);
            *(uint4*)&panel[row * SP + ch * 8] = v;
        }
        __syncthreads();
#pragma unroll
        for (int kt = 8; kt < 15; kt++) {
            if (kt + 1 < 15) LOADB(kt + 1, (kt + 1) & 1);
            MSTEP(kt & 1, (kt - 8) * 32);
        }
    }
#undef LOADB
#undef MSTEP
#undef BUILD_FEAT

    // ================= epilogue: C[row = l15 (+16i)][cols wave*80 + n*16 + (lane>>4)*4]
#pragma unroll
    for (int i = 0; i < 4; i++) {
        size_t gr = (size_t)(row0 + i * 16 + l15);
#pragma unroll
        for (int n = 0; n < 5; n++) {
            int col = wave * 80 + n * 16 + (lane >> 4) * 4;
            float4 v = make_float4(acc[i][n][0], acc[i][n][1], acc[i][n][2], acc[i][n][3]);
            if (MODE == 2) {
                float4 bias = *(const float4*)&bop[col];
                v.x += bias.x; v.y += bias.y; v.z += bias.z; v.w += bias.w;
            }
            ushort4 u;
            u.x = f2b(fmaxf(v.x, 0.f)); u.y = f2b(fmaxf(v.y, 0.f));
            u.z = f2b(fmaxf(v.z, 0.f)); u.w = f2b(fmaxf(v.w, 0.f));
            *(ushort4*)&outp[gr * HP + col] = u;
        }
    }
}

// ---------------------------------------------------------------- atom sum (bf16 in/out, fp32 accum)
__global__ __launch_bounds__(256) void k_atom_sum(
    const ushortT* __restrict__ msg, const int* __restrict__ a2b,
    ushortT* __restrict__ amsg, int nA) {
    int t = blockIdx.x * 256 + threadIdx.x;
    int a = t / 40, q = t - a * 40;
    if (a >= nA) return;
    float s[8];
#pragma unroll
    for (int e = 0; e < 8; e++) s[e] = 0.f;
#pragma unroll
    for (int j = 0; j < 6; j++) {
        int b = a2b[a * 6 + j];
        uint4 u = *(const uint4*)(msg + (size_t)b * HP + q * 8);
        upadd(u, s);
    }
    *(uint4*)(amsg + (size_t)a * HP + q * 8) = pk8(s);
}

// ---------------------------------------------------------------- mean pool (bf16 ah -> fp32 out), vectorized
__global__ __launch_bounds__(256) void k_pool(
    const ushortT* __restrict__ ah, float* __restrict__ out, int n_mols, int apm) {
    int t = blockIdx.x * 256 + threadIdx.x;
    int m = t / 75, c4 = t - m * 75;    // 75 float4-chunks of 300 cols
    if (m >= n_mols) return;
    float4 s = make_float4(0, 0, 0, 0);
    for (int u = 0; u < apm; u++) {
        ushort4 q = *(const ushort4*)&ah[(size_t)(m * apm + u) * HP + c4 * 4];
        s.x += b2f(q.x); s.y += b2f(q.y); s.z += b2f(q.z); s.w += b2f(q.w);
    }
    float inv = 1.0f / (float)apm;
    s.x *= inv; s.y *= inv; s.z *= inv; s.w *= inv;
    *(float4*)&out[(size_t)m * 300 + c4 * 4] = s;
}

// ---------------------------------------------------------------- launch
extern "C" void kernel_launch(void* const* d_in, const int* in_sizes, int n_in,
                              void* d_out, int out_size, void* d_ws, size_t ws_size,
                              hipStream_t stream) {
    const float* fa     = (const float*)d_in[0];
    const float* fb     = (const float*)d_in[1];
    const int*   a2b    = (const int*)d_in[2];
    const int*   b2a    = (const int*)d_in[3];
    const int*   b2revb = (const int*)d_in[4];
    const float* Wi     = (const float*)d_in[5];
    const float* Wh     = (const float*)d_in[6];
    const float* Wo     = (const float*)d_in[7];
    const float* bo     = (const float*)d_in[8];

    const int nA     = in_sizes[0] / 133;   // 200000
    const int nB     = in_sizes[1] / 147;   // 400000
    const int n_mols = out_size / 300;      // 10000
    const int apm    = nA / n_mols;         // 20

    char* p = (char*)d_ws;
    ushortT* Wipk = (ushortT*)p;  p += (size_t)51200 * 2;
    ushortT* Whpk = (ushortT*)p;  p += (size_t)102400 * 2;
    ushortT* Wopk = (ushortT*)p;  p += (size_t)153600 * 2;
    float*   bop  = (float*)p;    p += (size_t)HP * 4;
    p = (char*)(((uintptr_t)p + 255) & ~(uintptr_t)255);

    const size_t msgBytes  = (size_t)nB * HP * 2;
    const size_t amsgBytes = (size_t)nA * HP * 2;
    const size_t fbbBytes  = (size_t)nB * 160 * 2;
    const size_t faaBytes  = (size_t)nA * 160 * 2;
    const size_t headBytes = (size_t)(p - (char*)d_ws);
    const size_t baseNeed  = headBytes + 2 * msgBytes + amsgBytes;
    const bool use_fbb = ws_size >= baseNeed + fbbBytes;
    const bool use_faa = ws_size >= baseNeed + fbbBytes + faaBytes;

    ushortT* msgA = (ushortT*)p;  p += msgBytes;
    ushortT* msgB = (ushortT*)p;  p += msgBytes;
    ushortT* amsg = (ushortT*)p;  p += amsgBytes;
    ushortT* fbb  = use_fbb ? (ushortT*)p : nullptr;  p += use_fbb ? fbbBytes : 0;
    ushortT* faa  = use_faa ? (ushortT*)p : nullptr;
    ushortT* ah   = msgB;           // msgB dead after depth-2 MODE1 consumes it
    float*   out  = (float*)d_out;

    k_pack_weights<<<600, 256, 0, stream>>>(Wi, Wh, Wo, bo, Wipk, Whpk, Wopk, bop);
    if (use_fbb)
        k_pack_feat<147><<<(nB * 20 + 255) / 256, 256, 0, stream>>>(fb, fbb, nB);
    if (use_faa)
        k_pack_feat<133><<<(nA * 20 + 255) / 256, 256, 0, stream>>>(fa, faa, nA);

    const int asum_grid = (int)(((size_t)nA * 40 + 255) / 256);
    const int gB = nB / 64, gA = nA / 64;

    // GEMM1: msgA = relu(fbb @ Wi)
    if (use_fbb)
        k_mfma<0, true ><<<gB, 256, 0, stream>>>(fa, fb, fbb, nullptr, nullptr, nullptr, nullptr,
                                                 Wipk, Wipk, bop, msgA);
    else
        k_mfma<0, false><<<gB, 256, 0, stream>>>(fa, fb, nullptr, nullptr, nullptr, nullptr, nullptr,
                                                 Wipk, Wipk, bop, msgA);

    // depth 1: msgA -> msgB
    k_atom_sum<<<asum_grid, 256, 0, stream>>>(msgA, a2b, amsg, nA);
    if (use_fbb)
        k_mfma<1, true ><<<gB, 256, 0, stream>>>(fa, fb, fbb, amsg, msgA, b2a, b2revb,
                                                 Whpk, Wipk, bop, msgB);
    else
        k_mfma<1, false><<<gB, 256, 0, stream>>>(fa, fb, nullptr, amsg, msgA, b2a, b2revb,
                                                 Whpk, Wipk, bop, msgB);

    // depth 2: msgB -> msgA
    k_atom_sum<<<asum_grid, 256, 0, stream>>>(msgB, a2b, amsg, nA);
    if (use_fbb)
        k_mfma<1, true ><<<gB, 256, 0, stream>>>(fa, fb, fbb, amsg, msgB, b2a, b2revb,
                                                 Whpk, Wipk, bop, msgA);
    else
        k_mfma<1, false><<<gB, 256, 0, stream>>>(fa, fb, nullptr, amsg, msgB, b2a, b2revb,
                                                 Whpk, Wipk, bop, msgA);

    // readout: amsg = atomsum(msgA); ah = relu(concat(faa, amsg) @ Wo + b)
    k_atom_sum<<<asum_grid, 256, 0, stream>>>(msgA, a2b, amsg, nA);
    if (use_faa)
        k_mfma<2, true ><<<gA, 256, 0, stream>>>(fa, fb, faa, amsg, nullptr, nullptr, nullptr,
                                                 Wopk, Wopk, bop, ah);
    else
        k_mfma<2, false><<<gA, 256, 0, stream>>>(fa, fb, nullptr, amsg, nullptr, nullptr, nullptr,
                                                 Wopk, Wopk, bop, ah);
    k_pool<<<((n_mols * 75) + 255) / 256, 256, 0, stream>>>(ah, out, n_mols, apm);
}